// Round 9
// baseline (1567.766 us; speedup 1.0000x reference)
//
#include <hip/hip_runtime.h>
#include <math.h>

#define N_NODES 16000
#define N_EDGES 128000
#define KDIM 1024
#define N_RELS 7
#define NB_GOS 4096
#define KCAT (KDIM * (N_RELS + 1))     // 8192: [feat | agg r0..r6]
#define MPAD 16128                     // 63 * 256

#define BM 128
#define BN 128
#define BK 32
#define CAP2 (N_EDGES + N_RELS * BM)   // fallback path
#define NTILE_E (CAP2 / BM)

typedef __attribute__((ext_vector_type(8))) short bf16x8;
typedef __attribute__((ext_vector_type(8))) unsigned short u16x8;
typedef __attribute__((ext_vector_type(4))) float f32x4;

__device__ __forceinline__ unsigned short f2bf(float f) {
    union { float f; unsigned int u; } v; v.f = f;
    unsigned int u = v.u + 0x7FFFu + ((v.u >> 16) & 1u);   // RNE
    return (unsigned short)(u >> 16);
}

__device__ __forceinline__ void gload16(const void* g, void* lds) {
    __builtin_amdgcn_global_load_lds(
        (const __attribute__((address_space(1))) unsigned int*)g,
        (__attribute__((address_space(3))) unsigned int*)lds, 16, 0, 0);
}

// raw barrier with compiler-only memory fences (no hardware waitcnt emitted)
__device__ __forceinline__ void bar() {
    asm volatile("" ::: "memory");
    __builtin_amdgcn_s_barrier();
    asm volatile("" ::: "memory");
}

// ---------------- prep kernels ----------------

__global__ __launch_bounds__(256) void conv_bf16(const float* __restrict__ in,
                                                 unsigned short* __restrict__ out, int n8) {
    int i = blockIdx.x * 256 + threadIdx.x;
    if (i >= n8) return;
    const float4* in4 = (const float4*)in;
    float4 x = in4[2 * i], y = in4[2 * i + 1];
    u16x8 o;
    o[0] = f2bf(x.x); o[1] = f2bf(x.y); o[2] = f2bf(x.z); o[3] = f2bf(x.w);
    o[4] = f2bf(y.x); o[5] = f2bf(y.y); o[6] = f2bf(y.z); o[7] = f2bf(y.w);
    *(u16x8*)&out[(size_t)i * 8] = o;
}

__global__ __launch_bounds__(256) void conv_cat(const float* __restrict__ in,
                                                unsigned short* __restrict__ Acat) {
    int i = blockIdx.x * 256 + threadIdx.x;
    if (i >= N_NODES * (KDIM / 8)) return;
    int n = i >> 7, c8 = (i & 127) * 8;
    const float4* in4 = (const float4*)(in + (size_t)n * KDIM + c8);
    float4 x = in4[0], y = in4[1];
    u16x8 o;
    o[0] = f2bf(x.x); o[1] = f2bf(x.y); o[2] = f2bf(x.z); o[3] = f2bf(x.w);
    o[4] = f2bf(y.x); o[5] = f2bf(y.y); o[6] = f2bf(y.z); o[7] = f2bf(y.w);
    *(u16x8*)&Acat[(size_t)n * KCAT + c8] = o;
}

__global__ void transpose_w(const float* __restrict__ Wrel,
                            const float* __restrict__ Wloop,
                            unsigned short* __restrict__ WrelT,
                            unsigned short* __restrict__ WloopT) {
    __shared__ float t[32][33];
    int z = blockIdx.z;
    const float* src = (z < N_RELS) ? Wrel + (size_t)z * KDIM * KDIM : Wloop;
    unsigned short* dst = (z < N_RELS) ? WrelT + (size_t)z * KDIM * KDIM : WloopT;
    int tx = threadIdx.x, ty = threadIdx.y;
    int x = blockIdx.x * 32 + tx;
    int y0 = blockIdx.y * 32;
    #pragma unroll
    for (int j = 0; j < 4; j++)
        t[ty + 8 * j][tx] = src[(size_t)(y0 + ty + 8 * j) * KDIM + x];
    __syncthreads();
    #pragma unroll
    for (int j = 0; j < 4; j++) {
        int n = blockIdx.x * 32 + ty + 8 * j;
        dst[(size_t)n * KDIM + y0 + tx] = f2bf(t[tx][ty + 8 * j]);
    }
}

__global__ void transpose_cat(const float* __restrict__ Wrel,
                              const float* __restrict__ Wloop,
                              unsigned short* __restrict__ BT) {
    __shared__ float t[32][33];
    int z = blockIdx.z;
    const float* src = (z == 0) ? Wloop : Wrel + (size_t)(z - 1) * KDIM * KDIM;
    int tx = threadIdx.x, ty = threadIdx.y;
    int x = blockIdx.x * 32 + tx;
    int y0 = blockIdx.y * 32;
    #pragma unroll
    for (int j = 0; j < 4; j++)
        t[ty + 8 * j][tx] = src[(size_t)(y0 + ty + 8 * j) * KDIM + x];
    __syncthreads();
    #pragma unroll
    for (int j = 0; j < 4; j++) {
        int o = blockIdx.x * 32 + ty + 8 * j;
        BT[(size_t)o * KCAT + z * KDIM + y0 + tx] = f2bf(t[tx][ty + 8 * j]);
    }
}

// ---------------- dst-sort + aggregation (fast path) ----------------

__global__ void zero_ints(int* p, int n) {
    int i = blockIdx.x * 256 + threadIdx.x;
    if (i < n) p[i] = 0;
}

__global__ void hist_dst(const int* __restrict__ dst, int* cnt) {
    int e = blockIdx.x * 256 + threadIdx.x;
    if (e < N_EDGES) atomicAdd(&cnt[dst[e]], 1);
}

__global__ __launch_bounds__(1024) void scan_offs(const int* __restrict__ cnt,
                                                  int* __restrict__ offs) {
    __shared__ int part[1024];
    int t = threadIdx.x;
    int base = t * 16;
    int local[16];
    int s = 0;
    if (base < N_NODES) {
        #pragma unroll
        for (int j = 0; j < 16; j++) { local[j] = cnt[base + j]; s += local[j]; }
    }
    part[t] = s;
    __syncthreads();
    for (int d = 1; d < 1024; d <<= 1) {
        int v = (t >= d) ? part[t - d] : 0;
        __syncthreads();
        part[t] += v;
        __syncthreads();
    }
    if (base < N_NODES) {
        int ex = (t == 0) ? 0 : part[t - 1];
        #pragma unroll
        for (int j = 0; j < 16; j++) { offs[base + j] = ex; ex += local[j]; }
        if (base + 16 == N_NODES) offs[N_NODES] = ex;
    }
}

__global__ void scatter_dst(const int* __restrict__ src, const int* __restrict__ dst,
                            const int* __restrict__ et, const int* __restrict__ offs,
                            int* cursor, int* __restrict__ se) {
    int e = blockIdx.x * 256 + threadIdx.x;
    if (e < N_EDGES) {
        int d = dst[e];
        int p = atomicAdd(&cursor[d], 1);
        se[offs[d] + p] = (src[e] << 3) | et[e];
    }
}

__global__ __launch_bounds__(256) void aggregate(const float* __restrict__ feat,
                                                 const int* __restrict__ offs,
                                                 const int* __restrict__ se,
                                                 unsigned short* __restrict__ Acat) {
    int n = blockIdx.x;
    int t = threadIdx.x;
    int e0 = offs[n], e1 = offs[n + 1];
    float4 a0 = {0,0,0,0}, a1 = a0, a2 = a0, a3 = a0, a4 = a0, a5 = a0, a6 = a0;
    const float4* f4 = (const float4*)feat;
    for (int i = e0; i < e1; i++) {
        int v = se[i];
        int s = v >> 3, r = v & 7;
        float4 x = f4[(size_t)s * (KDIM / 4) + t];
        #define ADD4(a) { a.x += x.x; a.y += x.y; a.z += x.z; a.w += x.w; }
        switch (r) {
            case 0: ADD4(a0) break; case 1: ADD4(a1) break;
            case 2: ADD4(a2) break; case 3: ADD4(a3) break;
            case 4: ADD4(a4) break; case 5: ADD4(a5) break;
            default: ADD4(a6) break;
        }
        #undef ADD4
    }
    unsigned short* row = Acat + (size_t)n * KCAT + KDIM;
    #define ST4(rr, a) { ushort4 o; o.x = f2bf(a.x); o.y = f2bf(a.y); \
                         o.z = f2bf(a.z); o.w = f2bf(a.w); \
                         *(ushort4*)(row + rr * KDIM + t * 4) = o; }
    ST4(0, a0) ST4(1, a1) ST4(2, a2) ST4(3, a3) ST4(4, a4) ST4(5, a5) ST4(6, a6)
    #undef ST4
}

// ==== 256x256 GEMM, BK=64, 2 K-tiles/iter, register-pipelined fragments ====
// MODE 0: hb = bf16(A @ BT^T + bias)        MODE 2: out = sigmoid(... + |rad|)
// vs r8: fragment ds_reads for interval I+1 issue BEFORE interval I's MFMA
// (double-buffered frag regs afrX/afrY, bA/bB) so LDS reads complete UNDER the
// MFMA cluster; ONE barrier per interval. m-major XCD chunks (r8's n-outer
// doubled FETCH). Ledger (stage loads/interval: 2,6,2,6; vmcnt 2,6,2,6):
//  pre: stage buf0 full(8) + buf1{Alo,B}(6); vmcnt(6); bar; read afrX<-b0Alo,bA<-b0B
//  I1: read afrY<-b0Ahi  | stage b1Ahi(2t+1)      | MFMA(afrX,bA,MH0) | vm(2)
//  I2: read afrX<-b1Alo,bB<-b1B | stage b0{Alo,B}(2t+2) | MFMA(afrY,bA,MH1) | vm(6)
//  I3: read afrY<-b1Ahi  | stage b0Ahi(2t+2)      | MFMA(afrX,bB,MH0) | vm(2)
//  I4: read afrX<-b0Alo,bA<-b0B(2t+2!) | stage b1{Alo,B}(2t+3) | MFMA(afrY,bB,MH1) | vm(6)
// Hazards: every staged region's last read is consumed by MFMA >=1 barrier
// before the stage issues; every stage retires (counted vmcnt) + barrier
// before its first read. Tail: I2 vmcnt->0, stages guarded by nl.

template<int MODE, int KD>
__global__ __launch_bounds__(512, 2) void gemm256(
    const unsigned short* __restrict__ A,    // [Mpad][KD] bf16
    const unsigned short* __restrict__ BT,   // [N][KD] bf16 (rows = out cols)
    const float* __restrict__ br,            // bias / rad
    void* __restrict__ outv)
{
    __shared__ unsigned short As[2][256 * 64];
    __shared__ unsigned short Bs[2][256 * 64];

    const int tid = threadIdx.x;
    const int l = tid & 63, w = tid >> 6;
    const int wm = w >> 2, wn = w & 3;
    const int lrow = l & 15, lhi = l >> 4, lx = l & 7;

    // bijective XCD swizzle, m-major (consecutive wgids share the A slab)
    const int nwg = gridDim.x * gridDim.y;
    const int b = blockIdx.y * gridDim.x + blockIdx.x;
    const int q8 = nwg >> 3, r8 = nwg & 7;
    const int xcd = b & 7, idx = b >> 3;
    const int wg = (xcd < r8 ? xcd * (q8 + 1) : r8 * (q8 + 1) + (xcd - r8) * q8) + idx;
    const int m0 = (wg / gridDim.x) * 256;
    const int n0 = (wg % gridDim.x) * 256;

    const int NI = (KD >> 6) >> 1;

    const int rr = tid >> 3;                    // 0..63
    const int cc = (tid & 7) ^ (rr & 7);        // inverse-swizzled global chunk

    const unsigned short* gA = A + (size_t)(m0 + rr) * KD + cc * 8;
    const unsigned short* gB = BT + (size_t)(n0 + (rr & 31) + (rr >> 5) * 64) * KD + cc * 8;

    auto stageA = [&](int dbuf, int kt, int half) {
        #pragma unroll
        for (int j = 0; j < 2; j++)
            gload16(gA + (size_t)(j * 128 + half * 64) * KD + kt * 64,
                    &As[dbuf][(size_t)(w * 8 + j * 128 + half * 64) * 64]);
    };
    auto stageB = [&](int dbuf, int kt, int half) {
        #pragma unroll
        for (int j = 0; j < 2; j++)
            gload16(gB + (size_t)(j * 128 + half * 32) * KD + kt * 64,
                    &Bs[dbuf][(size_t)((w & 3) * 8 + (w >> 2) * 64 + j * 128 + half * 32) * 64]);
    };

    // prologue: buf0 = tile0 full (8 loads), buf1 = tile1 {Alo, B-full} (6)
    stageA(0, 0, 0); stageA(0, 0, 1); stageB(0, 0, 0); stageB(0, 0, 1);
    stageA(1, 1, 0); stageB(1, 1, 0); stageB(1, 1, 1);
    asm volatile("s_waitcnt vmcnt(6)" ::: "memory");   // retire buf0's 8
    bar();

    f32x4 acc[8][4] = {};
    bf16x8 afrX[4][2], afrY[4][2];
    bf16x8 bA0[2][2], bA1[2][2], bB0[2][2], bB1[2][2];

#define LDA(BUF, MH, DST) do { _Pragma("unroll")                              \
    for (int mi = 0; mi < 4; mi++) { _Pragma("unroll")                        \
        for (int ks = 0; ks < 2; ks++) {                                      \
            const int row_ = wm * 128 + (MH) * 64 + mi * 16 + lrow;           \
            const int ch_ = (ks * 4 + lhi) ^ lx;                              \
            DST[mi][ks] = *(const bf16x8*)&As[BUF][row_ * 64 + ch_ * 8];      \
        } } } while (0)

#define LDB(BUF, NH, DST) do { _Pragma("unroll")                              \
    for (int nj = 0; nj < 2; nj++) { _Pragma("unroll")                        \
        for (int ks = 0; ks < 2; ks++) {                                      \
            const int row_ = wn * 64 + (NH) * 32 + nj * 16 + lrow;            \
            const int ch_ = (ks * 4 + lhi) ^ lx;                              \
            DST[nj][ks] = *(const bf16x8*)&Bs[BUF][row_ * 64 + ch_ * 8];      \
        } } } while (0)

#define MM2(MH, AFR, B0, B1) do {                                             \
    __builtin_amdgcn_s_setprio(1);                                            \
    _Pragma("unroll")                                                         \
    for (int mi = 0; mi < 4; mi++) { _Pragma("unroll")                        \
        for (int nj = 0; nj < 2; nj++) { _Pragma("unroll")                    \
            for (int ks = 0; ks < 2; ks++) {                                  \
                acc[(MH)*4+mi][nj] = __builtin_amdgcn_mfma_f32_16x16x32_bf16( \
                    AFR[mi][ks], B0[nj][ks], acc[(MH)*4+mi][nj], 0, 0, 0);    \
                acc[(MH)*4+mi][2+nj] = __builtin_amdgcn_mfma_f32_16x16x32_bf16( \
                    AFR[mi][ks], B1[nj][ks], acc[(MH)*4+mi][2+nj], 0, 0, 0);  \
        } } }                                                                 \
    __builtin_amdgcn_s_setprio(0); } while (0)

    // pre-loop fragment reads for I1 of iter 0
    LDA(0, 0, afrX); LDB(0, 0, bA0); LDB(0, 1, bA1);

    for (int t = 0; t < NI; t++) {
        const bool nl = (t + 1 < NI);
        // I1: next-frags buf0-Ahi; stage buf1-Ahi(2t+1); MFMA tile2t MH0
        LDA(0, 1, afrY);
        stageA(1, 2 * t + 1, 1);
        MM2(0, afrX, bA0, bA1);
        asm volatile("s_waitcnt vmcnt(2)" ::: "memory");
        bar();
        // I2: next-frags buf1-{Alo,B}; stage buf0-{Alo,B}(2t+2); MFMA tile2t MH1
        LDA(1, 0, afrX); LDB(1, 0, bB0); LDB(1, 1, bB1);
        if (nl) { stageA(0, 2 * t + 2, 0); stageB(0, 2 * t + 2, 0); stageB(0, 2 * t + 2, 1); }
        MM2(1, afrY, bA0, bA1);
        if (nl) asm volatile("s_waitcnt vmcnt(6)" ::: "memory");
        else    asm volatile("s_waitcnt vmcnt(0)" ::: "memory");
        bar();
        // I3: next-frags buf1-Ahi; stage buf0-Ahi(2t+2); MFMA tile2t+1 MH0
        LDA(1, 1, afrY);
        if (nl) stageA(0, 2 * t + 2, 1);
        MM2(0, afrX, bB0, bB1);
        asm volatile("s_waitcnt vmcnt(2)" ::: "memory");
        bar();
        // I4: next-frags buf0-{Alo,B}(tile 2t+2); stage buf1-{Alo,B}(2t+3); MFMA tile2t+1 MH1
        LDA(0, 0, afrX); LDB(0, 0, bA0); LDB(0, 1, bA1);
        if (nl) { stageA(1, 2 * t + 3, 0); stageB(1, 2 * t + 3, 0); stageB(1, 2 * t + 3, 1); }
        MM2(1, afrY, bB0, bB1);
        if (nl) asm volatile("s_waitcnt vmcnt(6)" ::: "memory");
        bar();
    }
#undef LDA
#undef LDB
#undef MM2

    // epilogue — C/D layout: col = lane&15, row = (lane>>4)*4 + reg
    const int cl = l & 15, rh = (l >> 4) * 4;
    float brv[4];
    #pragma unroll
    for (int nj = 0; nj < 4; nj++) brv[nj] = br[n0 + wn * 64 + nj * 16 + cl];
    #pragma unroll
    for (int mi = 0; mi < 8; mi++) {
        #pragma unroll
        for (int r4 = 0; r4 < 4; r4++) {
            const int row = m0 + wm * 128 + mi * 16 + rh + r4;
            if (MODE == 2 && row >= N_NODES) continue;
            #pragma unroll
            for (int nj = 0; nj < 4; nj++) {
                const int col = n0 + wn * 64 + nj * 16 + cl;
                float x = acc[mi][nj][r4];
                if (MODE == 0) {
                    ((unsigned short*)outv)[(size_t)row * KDIM + col] = f2bf(x + brv[nj]);
                } else {
                    x += fabsf(brv[nj]);
                    ((float*)outv)[(size_t)row * (size_t)NB_GOS + col] =
                        1.0f / (1.0f + __expf(-x));
                }
            }
        }
    }
}

// ---------------- fallback 128x128 GEMM (rounds 3/4, unchanged) ----------------

__global__ void init_buckets(int* cnt, int* cursor, int* bucket) {
    int i = blockIdx.x * 256 + threadIdx.x;
    if (i < 8) { cnt[i] = 0; cursor[i] = 0; }
    if (i < CAP2) bucket[i] = -1;
}

__global__ __launch_bounds__(256) void count_etypes(const int* __restrict__ et, int* cnt) {
    __shared__ int lc[N_RELS];
    if (threadIdx.x < N_RELS) lc[threadIdx.x] = 0;
    __syncthreads();
    int e = blockIdx.x * 256 + threadIdx.x;
    if (e < N_EDGES) atomicAdd(&lc[et[e]], 1);
    __syncthreads();
    if (threadIdx.x < N_RELS) atomicAdd(&cnt[threadIdx.x], lc[threadIdx.x]);
}

__global__ void calc_offsets(const int* __restrict__ cnt, int* offs) {
    if (blockIdx.x == 0 && threadIdx.x == 0) {
        int acc = 0;
        offs[0] = 0;
        for (int r = 0; r < N_RELS; r++) {
            acc += ((cnt[r] + BM - 1) / BM) * BM;
            offs[r + 1] = acc;
        }
    }
}

__global__ __launch_bounds__(256) void scatter_edges(const int* __restrict__ et,
                                                     const int* __restrict__ offs,
                                                     int* cursor, int* bucket) {
    __shared__ int lc[N_RELS];
    __shared__ int lbase[N_RELS];
    if (threadIdx.x < N_RELS) lc[threadIdx.x] = 0;
    __syncthreads();
    int e = blockIdx.x * 256 + threadIdx.x;
    int r = 0, my = 0;
    bool valid = (e < N_EDGES);
    if (valid) { r = et[e]; my = atomicAdd(&lc[r], 1); }
    __syncthreads();
    if (threadIdx.x < N_RELS)
        lbase[threadIdx.x] = atomicAdd(&cursor[threadIdx.x], lc[threadIdx.x]);
    __syncthreads();
    if (valid) bucket[offs[r] + lbase[r] + my] = e;
}

template<int MODE>
__global__ __launch_bounds__(256) void mfma_gemm(
    const unsigned short* __restrict__ A,
    const unsigned short* __restrict__ BT,
    const float* __restrict__ br,
    float* __restrict__ out,
    const int* __restrict__ src,
    const int* __restrict__ dst,
    const int* __restrict__ bucket,
    const int* __restrict__ offs,
    int kd)
{
    __shared__ unsigned short As[BM * BK];
    __shared__ unsigned short Bs[BN * BK];
    __shared__ int s_src[BM];
    __shared__ int s_dst[BM];

    const int tid = threadIdx.x;
    const int l = tid & 63;
    const int w = tid >> 6;
    const int wr = w >> 1, wc = w & 1;

    const int nwg = gridDim.x * gridDim.y;
    const int b = blockIdx.y * gridDim.x + blockIdx.x;
    const int cpx = nwg >> 3;
    const int swz = (b & 7) * cpx + (b >> 3);
    const int n0 = (swz / gridDim.y) * BN;
    const int m0 = (swz % gridDim.y) * BM;

    const unsigned short* Bb = BT;
    if (MODE == 1) {
        int rel = -1;
        #pragma unroll
        for (int q = 0; q < N_RELS; q++)
            if (m0 >= offs[q] && m0 < offs[q + 1]) rel = q;
        if (rel < 0) return;
        Bb = BT + (size_t)rel * KDIM * KDIM;
        if (tid < BM) {
            int e = bucket[m0 + tid];
            s_src[tid] = (e >= 0) ? src[e] : -1;
            s_dst[tid] = (e >= 0) ? dst[e] : -1;
        }
        __syncthreads();
    }

    f32x4 acc[4][4] = {};

    const int s0 = tid, s1 = tid + 256;
    const int r0 = s0 >> 2, kc0 = (s0 & 3) * 8;
    const int r1 = s1 >> 2, kc1 = (s1 & 3) * 8;
    unsigned short* ldsA0 = As + (w * 64) * 8;
    unsigned short* ldsA1 = As + (w * 64 + 256) * 8;
    unsigned short* ldsB0 = Bs + (w * 64) * 8;
    unsigned short* ldsB1 = Bs + (w * 64 + 256) * 8;

    size_t arow0, arow1;
    if (MODE == 1) {
        int sr0 = s_src[r0]; arow0 = (sr0 < 0) ? 0 : (size_t)sr0;
        int sr1 = s_src[r1]; arow1 = (sr1 < 0) ? 0 : (size_t)sr1;
    } else {
        arow0 = (size_t)(m0 + r0);
        arow1 = (size_t)(m0 + r1);
    }
    const size_t brow0 = (size_t)(n0 + r0), brow1 = (size_t)(n0 + r1);

    const int fa = (wr * 64 + (l & 15)) * BK + (l >> 4) * 8;
    const int fb = (wc * 64 + (l & 15)) * BK + (l >> 4) * 8;

    for (int k0 = 0; k0 < kd; k0 += BK) {
        gload16(A + arow0 * kd + k0 + kc0, ldsA0);
        gload16(A + arow1 * kd + k0 + kc1, ldsA1);
        gload16(Bb + brow0 * kd + k0 + kc0, ldsB0);
        gload16(Bb + brow1 * kd + k0 + kc1, ldsB1);
        __syncthreads();

        bf16x8 a[4], bfr[4];
        #pragma unroll
        for (int mi = 0; mi < 4; mi++)
            a[mi] = *(const bf16x8*)&As[fa + mi * 16 * BK];
        #pragma unroll
        for (int nj = 0; nj < 4; nj++)
            bfr[nj] = *(const bf16x8*)&Bs[fb + nj * 16 * BK];
        #pragma unroll
        for (int mi = 0; mi < 4; mi++)
            #pragma unroll
            for (int nj = 0; nj < 4; nj++)
                acc[mi][nj] = __builtin_amdgcn_mfma_f32_16x16x32_bf16(a[mi], bfr[nj], acc[mi][nj], 0, 0, 0);
        __syncthreads();
    }

    const int cl = l & 15, rh = (l >> 4) * 4;
    #pragma unroll
    for (int mi = 0; mi < 4; mi++) {
        #pragma unroll
        for (int r4 = 0; r4 < 4; r4++) {
            const int row = wr * 64 + mi * 16 + rh + r4;
            if (MODE == 1) {
                const int d = s_dst[row];
                if (d >= 0) {
                    #pragma unroll
                    for (int nj = 0; nj < 4; nj++) {
                        const int col = n0 + wc * 64 + nj * 16 + cl;
                        atomicAdd(&out[(size_t)d * KDIM + col], acc[mi][nj][r4]);
                    }
                }
            } else if (MODE == 0) {
                #pragma unroll
                for (int nj = 0; nj < 4; nj++) {
                    const int col = n0 + wc * 64 + nj * 16 + cl;
                    out[(size_t)(m0 + row) * KDIM + col] = acc[mi][nj][r4] + br[col];
                }
            } else {
                #pragma unroll
                for (int nj = 0; nj < 4; nj++) {
                    const int col = n0 + wc * 64 + nj * 16 + cl;
                    float x = acc[mi][nj][r4] + fabsf(br[col]);
                    out[(size_t)(m0 + row) * (size_t)NB_GOS + col] = 1.0f / (1.0f + expf(-x));
                }
            }
        }
    }
}

// ---------------- launch ----------------

extern "C" void kernel_launch(void* const* d_in, const int* in_sizes, int n_in,
                              void* d_out, int out_size, void* d_ws, size_t ws_size,
                              hipStream_t stream) {
    const float* feat   = (const float*)d_in[0];
    const int*   src    = (const int*)d_in[1];
    const int*   dst    = (const int*)d_in[2];
    const int*   etypes = (const int*)d_in[3];
    const float* W_rel  = (const float*)d_in[4];
    const float* W_loop = (const float*)d_in[5];
    const float* bias   = (const float*)d_in[6];
    const float* go_emb = (const float*)d_in[7];
    const float* go_rad = (const float*)d_in[8];
    float* out = (float*)d_out;

    // ---- fast-path workspace layout (~323 MB) ----
    const size_t ACAT_B = (size_t)MPAD * KCAT * 2;      // 264,241,152
    const size_t HB_B   = (size_t)MPAD * KDIM * 2;      //  33,030,144 (bf16 h)
    const size_t BTC_B  = (size_t)KDIM * KCAT * 2;      //  16,777,216
    const size_t GOB_B  = (size_t)NB_GOS * KDIM * 2;    //   8,388,608
    const size_t CNT_B  = 16384 * 4;
    const size_t NEED   = ACAT_B + HB_B + BTC_B + GOB_B + 3 * CNT_B + (size_t)N_EDGES * 4;

    if (ws_size >= NEED) {
        char* p = (char*)d_ws;
        unsigned short* Acat  = (unsigned short*)p;  p += ACAT_B;
        unsigned short* hb    = (unsigned short*)p;  p += HB_B;
        unsigned short* BTcat = (unsigned short*)p;  p += BTC_B;
        unsigned short* gob   = (unsigned short*)p;  p += GOB_B;
        int* cnt    = (int*)p;                       p += CNT_B;
        int* cursor = (int*)p;                       p += CNT_B;
        int* offs   = (int*)p;                       p += CNT_B;
        int* se     = (int*)p;

        zero_ints<<<(2 * 16384 + 255) / 256, 256, 0, stream>>>(cnt, 2 * 16384);
        conv_cat<<<(N_NODES * (KDIM / 8) + 255) / 256, 256, 0, stream>>>(feat, Acat);
        conv_bf16<<<(NB_GOS * KDIM / 8 + 255) / 256, 256, 0, stream>>>(go_emb, gob, NB_GOS * KDIM / 8);
        {
            dim3 g(KDIM / 32, KDIM / 32, N_RELS + 1), bb(32, 8);
            transpose_cat<<<g, bb, 0, stream>>>(W_rel, W_loop, BTcat);
        }
        hist_dst<<<(N_EDGES + 255) / 256, 256, 0, stream>>>(dst, cnt);
        scan_offs<<<1, 1024, 0, stream>>>(cnt, offs);
        scatter_dst<<<(N_EDGES + 255) / 256, 256, 0, stream>>>(src, dst, etypes, offs, cursor, se);
        aggregate<<<N_NODES, 256, 0, stream>>>(feat, offs, se, Acat);

        // hb = bf16([feat | agg] @ [W_loop; W_rel]^T + bias)   (K = 8192)
        {
            dim3 g(KDIM / 256, MPAD / 256);    // (4, 63) -> 252 wgs
            gemm256<0, KCAT><<<g, 512, 0, stream>>>(Acat, BTcat, bias, hb);
        }
        // out = sigmoid(hb @ go^T + |rad|)   (K = 1024)
        {
            dim3 g(NB_GOS / 256, MPAD / 256);  // (16, 63) -> 1008 wgs
            gemm256<2, KDIM><<<g, 512, 0, stream>>>(hb, gob, go_rad, out);
        }
        return;
    }

    // ---- fallback: rounds-3/4 path (~124 MB ws) ----
    char* p = (char*)d_ws;
    float* h            = (float*)p;            p += (size_t)N_NODES * KDIM * 4;
    unsigned short* fb  = (unsigned short*)p;   p += (size_t)N_NODES * KDIM * 2;
    unsigned short* wrT = (unsigned short*)p;   p += (size_t)N_RELS * KDIM * KDIM * 2;
    unsigned short* wlT = (unsigned short*)p;   p += (size_t)KDIM * KDIM * 2;
    unsigned short* gob = (unsigned short*)p;   p += (size_t)NB_GOS * KDIM * 2;
    int* cnt    = (int*)p;
    int* cursor = cnt + 8;
    int* offs   = cursor + 8;
    int* bucket = offs + 16;

    conv_bf16<<<(N_NODES * KDIM / 8 + 255) / 256, 256, 0, stream>>>(feat, fb, N_NODES * KDIM / 8);
    conv_bf16<<<(NB_GOS * KDIM / 8 + 255) / 256, 256, 0, stream>>>(go_emb, gob, NB_GOS * KDIM / 8);
    {
        dim3 g(KDIM / 32, KDIM / 32, N_RELS + 1), bb(32, 8);
        transpose_w<<<g, bb, 0, stream>>>(W_rel, W_loop, wrT, wlT);
    }
    init_buckets<<<(CAP2 + 255) / 256, 256, 0, stream>>>(cnt, cursor, bucket);
    count_etypes<<<(N_EDGES + 255) / 256, 256, 0, stream>>>(etypes, cnt);
    calc_offsets<<<1, 64, 0, stream>>>(cnt, offs);
    scatter_edges<<<(N_EDGES + 255) / 256, 256, 0, stream>>>(etypes, offs, cursor, bucket);
    {
        dim3 g(KDIM / BN, N_NODES / BM);
        mfma_gemm<0><<<g, 256, 0, stream>>>(fb, wlT, bias, h, nullptr, nullptr, nullptr, nullptr, KDIM);
    }
    {
        dim3 g(KDIM / BN, NTILE_E);
        mfma_gemm<1><<<g, 256, 0, stream>>>(fb, wrT, nullptr, h, src, dst, bucket, offs, KDIM);
    }
    conv_bf16<<<(N_NODES * KDIM / 8 + 255) / 256, 256, 0, stream>>>(h, fb, N_NODES * KDIM / 8);
    {
        dim3 g(NB_GOS / BN, N_NODES / BM);
        mfma_gemm<2><<<g, 256, 0, stream>>>(fb, gob, go_rad, out, nullptr, nullptr, nullptr, nullptr, KDIM);
    }
}

// Round 10
// 580.890 us; speedup vs baseline: 2.6989x; 2.6989x over previous
//
#include <hip/hip_runtime.h>
#include <math.h>

#define N_NODES 16000
#define N_EDGES 128000
#define KDIM 1024
#define N_RELS 7
#define NB_GOS 4096
#define KCAT (KDIM * (N_RELS + 1))     // 8192: [feat | agg r0..r6]
#define MPAD 16128                     // 63 * 256

#define BM 128
#define BN 128
#define BK 32
#define CAP2 (N_EDGES + N_RELS * BM)   // fallback path
#define NTILE_E (CAP2 / BM)

typedef __attribute__((ext_vector_type(8))) short bf16x8;
typedef __attribute__((ext_vector_type(8))) unsigned short u16x8;
typedef __attribute__((ext_vector_type(4))) float f32x4;

__device__ __forceinline__ unsigned short f2bf(float f) {
    union { float f; unsigned int u; } v; v.f = f;
    unsigned int u = v.u + 0x7FFFu + ((v.u >> 16) & 1u);   // RNE
    return (unsigned short)(u >> 16);
}

__device__ __forceinline__ float bf2f(unsigned short u) {
    union { unsigned int u; float f; } v; v.u = (unsigned int)u << 16;
    return v.f;
}

__device__ __forceinline__ void gload16(const void* g, void* lds) {
    __builtin_amdgcn_global_load_lds(
        (const __attribute__((address_space(1))) unsigned int*)g,
        (__attribute__((address_space(3))) unsigned int*)lds, 16, 0, 0);
}

// ---------------- prep kernels ----------------

__global__ __launch_bounds__(256) void conv_bf16(const float* __restrict__ in,
                                                 unsigned short* __restrict__ out, int n8) {
    int i = blockIdx.x * 256 + threadIdx.x;
    if (i >= n8) return;
    const float4* in4 = (const float4*)in;
    float4 x = in4[2 * i], y = in4[2 * i + 1];
    u16x8 o;
    o[0] = f2bf(x.x); o[1] = f2bf(x.y); o[2] = f2bf(x.z); o[3] = f2bf(x.w);
    o[4] = f2bf(y.x); o[5] = f2bf(y.y); o[6] = f2bf(y.z); o[7] = f2bf(y.w);
    *(u16x8*)&out[(size_t)i * 8] = o;
}

__global__ __launch_bounds__(256) void conv_cat(const float* __restrict__ in,
                                                unsigned short* __restrict__ Acat) {
    int i = blockIdx.x * 256 + threadIdx.x;
    if (i >= N_NODES * (KDIM / 8)) return;
    int n = i >> 7, c8 = (i & 127) * 8;
    const float4* in4 = (const float4*)(in + (size_t)n * KDIM + c8);
    float4 x = in4[0], y = in4[1];
    u16x8 o;
    o[0] = f2bf(x.x); o[1] = f2bf(x.y); o[2] = f2bf(x.z); o[3] = f2bf(x.w);
    o[4] = f2bf(y.x); o[5] = f2bf(y.y); o[6] = f2bf(y.z); o[7] = f2bf(y.w);
    *(u16x8*)&Acat[(size_t)n * KCAT + c8] = o;
}

__global__ void transpose_w(const float* __restrict__ Wrel,
                            const float* __restrict__ Wloop,
                            unsigned short* __restrict__ WrelT,
                            unsigned short* __restrict__ WloopT) {
    __shared__ float t[32][33];
    int z = blockIdx.z;
    const float* src = (z < N_RELS) ? Wrel + (size_t)z * KDIM * KDIM : Wloop;
    unsigned short* dst = (z < N_RELS) ? WrelT + (size_t)z * KDIM * KDIM : WloopT;
    int tx = threadIdx.x, ty = threadIdx.y;
    int x = blockIdx.x * 32 + tx;
    int y0 = blockIdx.y * 32;
    #pragma unroll
    for (int j = 0; j < 4; j++)
        t[ty + 8 * j][tx] = src[(size_t)(y0 + ty + 8 * j) * KDIM + x];
    __syncthreads();
    #pragma unroll
    for (int j = 0; j < 4; j++) {
        int n = blockIdx.x * 32 + ty + 8 * j;
        dst[(size_t)n * KDIM + y0 + tx] = f2bf(t[tx][ty + 8 * j]);
    }
}

__global__ void transpose_cat(const float* __restrict__ Wrel,
                              const float* __restrict__ Wloop,
                              unsigned short* __restrict__ BT) {
    __shared__ float t[32][33];
    int z = blockIdx.z;
    const float* src = (z == 0) ? Wloop : Wrel + (size_t)(z - 1) * KDIM * KDIM;
    int tx = threadIdx.x, ty = threadIdx.y;
    int x = blockIdx.x * 32 + tx;
    int y0 = blockIdx.y * 32;
    #pragma unroll
    for (int j = 0; j < 4; j++)
        t[ty + 8 * j][tx] = src[(size_t)(y0 + ty + 8 * j) * KDIM + x];
    __syncthreads();
    #pragma unroll
    for (int j = 0; j < 4; j++) {
        int o = blockIdx.x * 32 + ty + 8 * j;
        BT[(size_t)o * KCAT + z * KDIM + y0 + tx] = f2bf(t[tx][ty + 8 * j]);
    }
}

// ---------------- dst-sort + aggregation (fast path) ----------------

__global__ void zero_ints(int* p, int n) {
    int i = blockIdx.x * 256 + threadIdx.x;
    if (i < n) p[i] = 0;
}

__global__ void hist_dst(const int* __restrict__ dst, int* cnt) {
    int e = blockIdx.x * 256 + threadIdx.x;
    if (e < N_EDGES) atomicAdd(&cnt[dst[e]], 1);
}

__global__ __launch_bounds__(1024) void scan_offs(const int* __restrict__ cnt,
                                                  int* __restrict__ offs) {
    __shared__ int part[1024];
    int t = threadIdx.x;
    int base = t * 16;
    int local[16];
    int s = 0;
    if (base < N_NODES) {
        #pragma unroll
        for (int j = 0; j < 16; j++) { local[j] = cnt[base + j]; s += local[j]; }
    }
    part[t] = s;
    __syncthreads();
    for (int d = 1; d < 1024; d <<= 1) {
        int v = (t >= d) ? part[t - d] : 0;
        __syncthreads();
        part[t] += v;
        __syncthreads();
    }
    if (base < N_NODES) {
        int ex = (t == 0) ? 0 : part[t - 1];
        #pragma unroll
        for (int j = 0; j < 16; j++) { offs[base + j] = ex; ex += local[j]; }
        if (base + 16 == N_NODES) offs[N_NODES] = ex;
    }
}

__global__ void scatter_dst(const int* __restrict__ src, const int* __restrict__ dst,
                            const int* __restrict__ et, const int* __restrict__ offs,
                            int* cursor, int* __restrict__ se) {
    int e = blockIdx.x * 256 + threadIdx.x;
    if (e < N_EDGES) {
        int d = dst[e];
        int p = atomicAdd(&cursor[d], 1);
        se[offs[d] + p] = (src[e] << 3) | et[e];
    }
}

// per-node aggregation: reads src rows in BF16 from Acat's feat region
// (halves HBM/L3 read bytes vs fp32 feat), fp32 accumulate, bf16 store.
// Reads cols [0,1024) of arbitrary rows; writes cols [1024,8192) of own row.
__global__ __launch_bounds__(256) void aggregate(const int* __restrict__ offs,
                                                 const int* __restrict__ se,
                                                 unsigned short* __restrict__ Acat) {
    int n = blockIdx.x;
    int t = threadIdx.x;
    int e0 = offs[n], e1 = offs[n + 1];
    float4 a0 = {0,0,0,0}, a1 = a0, a2 = a0, a3 = a0, a4 = a0, a5 = a0, a6 = a0;
    for (int i = e0; i < e1; i++) {
        int v = se[i];                      // wave-uniform
        int s = v >> 3, r = v & 7;
        ushort4 q = *(const ushort4*)&Acat[(size_t)s * KCAT + t * 4];
        float4 x = { bf2f(q.x), bf2f(q.y), bf2f(q.z), bf2f(q.w) };
        #define ADD4(a) { a.x += x.x; a.y += x.y; a.z += x.z; a.w += x.w; }
        switch (r) {                        // uniform branch (same edge blockwide)
            case 0: ADD4(a0) break; case 1: ADD4(a1) break;
            case 2: ADD4(a2) break; case 3: ADD4(a3) break;
            case 4: ADD4(a4) break; case 5: ADD4(a5) break;
            default: ADD4(a6) break;
        }
        #undef ADD4
    }
    unsigned short* row = Acat + (size_t)n * KCAT + KDIM;
    #define ST4(rr, a) { ushort4 o; o.x = f2bf(a.x); o.y = f2bf(a.y); \
                         o.z = f2bf(a.z); o.w = f2bf(a.w); \
                         *(ushort4*)(row + rr * KDIM + t * 4) = o; }
    ST4(0, a0) ST4(1, a1) ST4(2, a2) ST4(3, a3) ST4(4, a4) ST4(5, a5) ST4(6, a6)
    #undef ST4
}

// ======== 256x256 GEMM, BK=64, 2 K-tiles/iter, 4 fat phases (32 MFMA each) ====
// MODE 0: hb = bf16(A @ BT^T + bias)        MODE 2: out = sigmoid(... + |rad|)
// r8 structure (verified 296 us / 914 TF): fragment reuse (24 ds_read_b128 per
// wave per K-tile), fat phases, counted vmcnt, n-outer XCD chunks (B panel
// L2-resident per XCD). r9's cross-interval register pipeline REVERTED: it
// needed ~190 arch VGPRs vs the 128 budget (acc holds 128 AGPRs of the
// 256-unified cap at 2 waves/SIMD) -> spill -> 1.7 GB scratch writes, 3x slow.
// Ledger (per wave, 2 loads per stage call):
//  P1: LDA(0,0) LDB(0,0->b0) LDB(0,1->b1); stage Ahi,Bhi(2t+1)->buf1 | 32 MFMA
//  P2: LDA(0,1); stage Alo,Blo(2t+2)->buf0 | 32 MFMA | vmcnt(4)
//  P3: LDA(1,0) LDB->b0,b1;  stage Ahi,Bhi(2t+2)->buf0 | 32 MFMA
//  P4: LDA(1,1); stage Alo,Blo(2t+3)->buf1 | 32 MFMA | vmcnt(4)

template<int MODE, int KD>
__global__ __launch_bounds__(512, 2) void gemm256(
    const unsigned short* __restrict__ A,    // [Mpad][KD] bf16
    const unsigned short* __restrict__ BT,   // [N][KD] bf16 (rows = out cols)
    const float* __restrict__ br,            // bias / rad
    void* __restrict__ outv)
{
    __shared__ unsigned short As[2][256 * 64];
    __shared__ unsigned short Bs[2][256 * 64];

    const int tid = threadIdx.x;
    const int l = tid & 63, w = tid >> 6;
    const int wm = w >> 2, wn = w & 3;
    const int lrow = l & 15, lhi = l >> 4, lx = l & 7;

    // bijective XCD swizzle; n-OUTER decomposition: each XCD's resident wgs
    // share one 256-col B panel -> B stays L2-resident.
    const int nwg = gridDim.x * gridDim.y;
    const int b = blockIdx.y * gridDim.x + blockIdx.x;
    const int q8 = nwg >> 3, r8 = nwg & 7;
    const int xcd = b & 7, idx = b >> 3;
    const int wg = (xcd < r8 ? xcd * (q8 + 1) : r8 * (q8 + 1) + (xcd - r8) * q8) + idx;
    const int m0 = (wg % gridDim.y) * 256;
    const int n0 = (wg / gridDim.y) * 256;

    const int NI = (KD >> 6) >> 1;

    const int rr = tid >> 3;                    // 0..63
    const int cc = (tid & 7) ^ (rr & 7);        // inverse-swizzled global chunk

    const unsigned short* gA = A + (size_t)(m0 + rr) * KD + cc * 8;
    const unsigned short* gB = BT + (size_t)(n0 + (rr & 31) + (rr >> 5) * 64) * KD + cc * 8;

    auto stageA = [&](int dbuf, int kt, int half) {
        #pragma unroll
        for (int j = 0; j < 2; j++)
            gload16(gA + (size_t)(j * 128 + half * 64) * KD + kt * 64,
                    &As[dbuf][(size_t)(w * 8 + j * 128 + half * 64) * 64]);
    };
    // B half = nh stripes: rows {0-31,64-95,128-159,192-223} (+32 for half=1)
    auto stageB = [&](int dbuf, int kt, int half) {
        #pragma unroll
        for (int j = 0; j < 2; j++)
            gload16(gB + (size_t)(j * 128 + half * 32) * KD + kt * 64,
                    &Bs[dbuf][(size_t)((w & 3) * 8 + (w >> 2) * 64 + j * 128 + half * 32) * 64]);
    };

    // prologue: tile0 all 4 halves + tile1 lo halves; retire tile0, leave 4
    stageA(0, 0, 0); stageB(0, 0, 0); stageA(0, 0, 1); stageB(0, 0, 1);
    stageA(1, 1, 0); stageB(1, 1, 0);
    asm volatile("s_waitcnt vmcnt(4)" ::: "memory");
    __builtin_amdgcn_s_barrier();

    f32x4 acc[8][4] = {};
    bf16x8 afr[4][2], b0[2][2], b1[2][2];

#define LDA(BUF, MH) do { _Pragma("unroll")                                   \
    for (int mi = 0; mi < 4; mi++) { _Pragma("unroll")                        \
        for (int ks = 0; ks < 2; ks++) {                                      \
            const int row_ = wm * 128 + (MH) * 64 + mi * 16 + lrow;           \
            const int ch_ = (ks * 4 + lhi) ^ lx;                              \
            afr[mi][ks] = *(const bf16x8*)&As[BUF][row_ * 64 + ch_ * 8];      \
        } } } while (0)

#define LDB(BUF, NH, DST) do { _Pragma("unroll")                              \
    for (int nj = 0; nj < 2; nj++) { _Pragma("unroll")                        \
        for (int ks = 0; ks < 2; ks++) {                                      \
            const int row_ = wn * 64 + (NH) * 32 + nj * 16 + lrow;            \
            const int ch_ = (ks * 4 + lhi) ^ lx;                              \
            DST[nj][ks] = *(const bf16x8*)&Bs[BUF][row_ * 64 + ch_ * 8];      \
        } } } while (0)

// one fat phase: barrier, 32 MFMA (MH x both NH quadrants), covered by setprio
#define MM2(MH) do {                                                          \
    __builtin_amdgcn_s_barrier();                                             \
    __builtin_amdgcn_s_setprio(1);                                            \
    _Pragma("unroll")                                                         \
    for (int mi = 0; mi < 4; mi++) { _Pragma("unroll")                        \
        for (int nj = 0; nj < 2; nj++) { _Pragma("unroll")                    \
            for (int ks = 0; ks < 2; ks++) {                                  \
                acc[(MH)*4+mi][nj] = __builtin_amdgcn_mfma_f32_16x16x32_bf16( \
                    afr[mi][ks], b0[nj][ks], acc[(MH)*4+mi][nj], 0, 0, 0);    \
                acc[(MH)*4+mi][2+nj] = __builtin_amdgcn_mfma_f32_16x16x32_bf16( \
                    afr[mi][ks], b1[nj][ks], acc[(MH)*4+mi][2+nj], 0, 0, 0);  \
        } } }                                                                 \
    __builtin_amdgcn_s_setprio(0); } while (0)

    for (int t = 0; t < NI; t++) {
        const bool nl = (t + 1 < NI);
        // P1: tile 2t (buf0), MH0 x {NH0,NH1}
        LDA(0, 0); LDB(0, 0, b0); LDB(0, 1, b1);
        stageA(1, 2 * t + 1, 1); stageB(1, 2 * t + 1, 1);
        MM2(0);
        __builtin_amdgcn_s_barrier();
        // P2: tile 2t, MH1 (b0,b1 reused)
        LDA(0, 1);
        if (nl) { stageA(0, 2 * t + 2, 0); stageB(0, 2 * t + 2, 0); }
        MM2(1);
        if (nl) asm volatile("s_waitcnt vmcnt(4)" ::: "memory");
        else    asm volatile("s_waitcnt vmcnt(0)" ::: "memory");
        __builtin_amdgcn_s_barrier();
        // P3: tile 2t+1 (buf1), MH0
        LDA(1, 0); LDB(1, 0, b0); LDB(1, 1, b1);
        if (nl) { stageA(0, 2 * t + 2, 1); stageB(0, 2 * t + 2, 1); }
        MM2(0);
        __builtin_amdgcn_s_barrier();
        // P4: tile 2t+1, MH1
        LDA(1, 1);
        if (nl) { stageA(1, 2 * t + 3, 0); stageB(1, 2 * t + 3, 0); }
        MM2(1);
        if (nl) asm volatile("s_waitcnt vmcnt(4)" ::: "memory");
        else    asm volatile("s_waitcnt vmcnt(0)" ::: "memory");
        __builtin_amdgcn_s_barrier();
    }
#undef LDA
#undef LDB
#undef MM2

    // epilogue — C/D layout: col = lane&15, row = (lane>>4)*4 + reg
    const int cl = l & 15, rh = (l >> 4) * 4;
    float brv[4];
    #pragma unroll
    for (int nj = 0; nj < 4; nj++) brv[nj] = br[n0 + wn * 64 + nj * 16 + cl];
    #pragma unroll
    for (int mi = 0; mi < 8; mi++) {
        #pragma unroll
        for (int r4 = 0; r4 < 4; r4++) {
            const int row = m0 + wm * 128 + mi * 16 + rh + r4;
            if (MODE == 2 && row >= N_NODES) continue;
            #pragma unroll
            for (int nj = 0; nj < 4; nj++) {
                const int col = n0 + wn * 64 + nj * 16 + cl;
                float x = acc[mi][nj][r4];
                if (MODE == 0) {
                    ((unsigned short*)outv)[(size_t)row * KDIM + col] = f2bf(x + brv[nj]);
                } else {
                    x += fabsf(brv[nj]);
                    ((float*)outv)[(size_t)row * (size_t)NB_GOS + col] =
                        1.0f / (1.0f + __expf(-x));
                }
            }
        }
    }
}

// ---------------- fallback 128x128 GEMM (rounds 3/4, unchanged) ----------------

__global__ void init_buckets(int* cnt, int* cursor, int* bucket) {
    int i = blockIdx.x * 256 + threadIdx.x;
    if (i < 8) { cnt[i] = 0; cursor[i] = 0; }
    if (i < CAP2) bucket[i] = -1;
}

__global__ __launch_bounds__(256) void count_etypes(const int* __restrict__ et, int* cnt) {
    __shared__ int lc[N_RELS];
    if (threadIdx.x < N_RELS) lc[threadIdx.x] = 0;
    __syncthreads();
    int e = blockIdx.x * 256 + threadIdx.x;
    if (e < N_EDGES) atomicAdd(&lc[et[e]], 1);
    __syncthreads();
    if (threadIdx.x < N_RELS) atomicAdd(&cnt[threadIdx.x], lc[threadIdx.x]);
}

__global__ void calc_offsets(const int* __restrict__ cnt, int* offs) {
    if (blockIdx.x == 0 && threadIdx.x == 0) {
        int acc = 0;
        offs[0] = 0;
        for (int r = 0; r < N_RELS; r++) {
            acc += ((cnt[r] + BM - 1) / BM) * BM;
            offs[r + 1] = acc;
        }
    }
}

__global__ __launch_bounds__(256) void scatter_edges(const int* __restrict__ et,
                                                     const int* __restrict__ offs,
                                                     int* cursor, int* bucket) {
    __shared__ int lc[N_RELS];
    __shared__ int lbase[N_RELS];
    if (threadIdx.x < N_RELS) lc[threadIdx.x] = 0;
    __syncthreads();
    int e = blockIdx.x * 256 + threadIdx.x;
    int r = 0, my = 0;
    bool valid = (e < N_EDGES);
    if (valid) { r = et[e]; my = atomicAdd(&lc[r], 1); }
    __syncthreads();
    if (threadIdx.x < N_RELS)
        lbase[threadIdx.x] = atomicAdd(&cursor[threadIdx.x], lc[threadIdx.x]);
    __syncthreads();
    if (valid) bucket[offs[r] + lbase[r] + my] = e;
}

template<int MODE>
__global__ __launch_bounds__(256) void mfma_gemm(
    const unsigned short* __restrict__ A,
    const unsigned short* __restrict__ BT,
    const float* __restrict__ br,
    float* __restrict__ out,
    const int* __restrict__ src,
    const int* __restrict__ dst,
    const int* __restrict__ bucket,
    const int* __restrict__ offs,
    int kd)
{
    __shared__ unsigned short As[BM * BK];
    __shared__ unsigned short Bs[BN * BK];
    __shared__ int s_src[BM];
    __shared__ int s_dst[BM];

    const int tid = threadIdx.x;
    const int l = tid & 63;
    const int w = tid >> 6;
    const int wr = w >> 1, wc = w & 1;

    const int nwg = gridDim.x * gridDim.y;
    const int b = blockIdx.y * gridDim.x + blockIdx.x;
    const int cpx = nwg >> 3;
    const int swz = (b & 7) * cpx + (b >> 3);
    const int n0 = (swz / gridDim.y) * BN;
    const int m0 = (swz % gridDim.y) * BM;

    const unsigned short* Bb = BT;
    if (MODE == 1) {
        int rel = -1;
        #pragma unroll
        for (int q = 0; q < N_RELS; q++)
            if (m0 >= offs[q] && m0 < offs[q + 1]) rel = q;
        if (rel < 0) return;
        Bb = BT + (size_t)rel * KDIM * KDIM;
        if (tid < BM) {
            int e = bucket[m0 + tid];
            s_src[tid] = (e >= 0) ? src[e] : -1;
            s_dst[tid] = (e >= 0) ? dst[e] : -1;
        }
        __syncthreads();
    }

    f32x4 acc[4][4] = {};

    const int s0 = tid, s1 = tid + 256;
    const int r0 = s0 >> 2, kc0 = (s0 & 3) * 8;
    const int r1 = s1 >> 2, kc1 = (s1 & 3) * 8;
    unsigned short* ldsA0 = As + (w * 64) * 8;
    unsigned short* ldsA1 = As + (w * 64 + 256) * 8;
    unsigned short* ldsB0 = Bs + (w * 64) * 8;
    unsigned short* ldsB1 = Bs + (w * 64 + 256) * 8;

    size_t arow0, arow1;
    if (MODE == 1) {
        int sr0 = s_src[r0]; arow0 = (sr0 < 0) ? 0 : (size_t)sr0;
        int sr1 = s_src[r1]; arow1 = (sr1 < 0) ? 0 : (size_t)sr1;
    } else {
        arow0 = (size_t)(m0 + r0);
        arow1 = (size_t)(m0 + r1);
    }
    const size_t brow0 = (size_t)(n0 + r0), brow1 = (size_t)(n0 + r1);

    const int fa = (wr * 64 + (l & 15)) * BK + (l >> 4) * 8;
    const int fb = (wc * 64 + (l & 15)) * BK + (l >> 4) * 8;

    for (int k0 = 0; k0 < kd; k0 += BK) {
        gload16(A + arow0 * kd + k0 + kc0, ldsA0);
        gload16(A + arow1 * kd + k0 + kc1, ldsA1);
        gload16(Bb + brow0 * kd + k0 + kc0, ldsB0);
        gload16(Bb + brow1 * kd + k0 + kc1, ldsB1);
        __syncthreads();

        bf16x8 a[4], bfr[4];
        #pragma unroll
        for (int mi = 0; mi < 4; mi++)
            a[mi] = *(const bf16x8*)&As[fa + mi * 16 * BK];
        #pragma unroll
        for (int nj = 0; nj < 4; nj++)
            bfr[nj] = *(const bf16x8*)&Bs[fb + nj * 16 * BK];
        #pragma unroll
        for (int mi = 0; mi < 4; mi++)
            #pragma unroll
            for (int nj = 0; nj < 4; nj++)
                acc[mi][nj] = __builtin_amdgcn_mfma_f32_16x16x32_bf16(a[mi], bfr[nj], acc[mi][nj], 0, 0, 0);
        __syncthreads();
    }

    const int cl = l & 15, rh = (l >> 4) * 4;
    #pragma unroll
    for (int mi = 0; mi < 4; mi++) {
        #pragma unroll
        for (int r4 = 0; r4 < 4; r4++) {
            const int row = wr * 64 + mi * 16 + rh + r4;
            if (MODE == 1) {
                const int d = s_dst[row];
                if (d >= 0) {
                    #pragma unroll
                    for (int nj = 0; nj < 4; nj++) {
                        const int col = n0 + wc * 64 + nj * 16 + cl;
                        atomicAdd(&out[(size_t)d * KDIM + col], acc[mi][nj][r4]);
                    }
                }
            } else if (MODE == 0) {
                #pragma unroll
                for (int nj = 0; nj < 4; nj++) {
                    const int col = n0 + wc * 64 + nj * 16 + cl;
                    out[(size_t)(m0 + row) * KDIM + col] = acc[mi][nj][r4] + br[col];
                }
            } else {
                #pragma unroll
                for (int nj = 0; nj < 4; nj++) {
                    const int col = n0 + wc * 64 + nj * 16 + cl;
                    float x = acc[mi][nj][r4] + fabsf(br[col]);
                    out[(size_t)(m0 + row) * (size_t)NB_GOS + col] = 1.0f / (1.0f + expf(-x));
                }
            }
        }
    }
}

// ---------------- launch ----------------

extern "C" void kernel_launch(void* const* d_in, const int* in_sizes, int n_in,
                              void* d_out, int out_size, void* d_ws, size_t ws_size,
                              hipStream_t stream) {
    const float* feat   = (const float*)d_in[0];
    const int*   src    = (const int*)d_in[1];
    const int*   dst    = (const int*)d_in[2];
    const int*   etypes = (const int*)d_in[3];
    const float* W_rel  = (const float*)d_in[4];
    const float* W_loop = (const float*)d_in[5];
    const float* bias   = (const float*)d_in[6];
    const float* go_emb = (const float*)d_in[7];
    const float* go_rad = (const float*)d_in[8];
    float* out = (float*)d_out;

    // ---- fast-path workspace layout (~323 MB) ----
    const size_t ACAT_B = (size_t)MPAD * KCAT * 2;      // 264,241,152
    const size_t HB_B   = (size_t)MPAD * KDIM * 2;      //  33,030,144 (bf16 h)
    const size_t BTC_B  = (size_t)KDIM * KCAT * 2;      //  16,777,216
    const size_t GOB_B  = (size_t)NB_GOS * KDIM * 2;    //   8,388,608
    const size_t CNT_B  = 16384 * 4;
    const size_t NEED   = ACAT_B + HB_B + BTC_B + GOB_B + 3 * CNT_B + (size_t)N_EDGES * 4;

    if (ws_size >= NEED) {
        char* p = (char*)d_ws;
        unsigned short* Acat  = (unsigned short*)p;  p += ACAT_B;
        unsigned short* hb    = (unsigned short*)p;  p += HB_B;
        unsigned short* BTcat = (unsigned short*)p;  p += BTC_B;
        unsigned short* gob   = (unsigned short*)p;  p += GOB_B;
        int* cnt    = (int*)p;                       p += CNT_B;
        int* cursor = (int*)p;                       p += CNT_B;
        int* offs   = (int*)p;                       p += CNT_B;
        int* se     = (int*)p;

        zero_ints<<<(2 * 16384 + 255) / 256, 256, 0, stream>>>(cnt, 2 * 16384);
        conv_cat<<<(N_NODES * (KDIM / 8) + 255) / 256, 256, 0, stream>>>(feat, Acat);
        conv_bf16<<<(NB_GOS * KDIM / 8 + 255) / 256, 256, 0, stream>>>(go_emb, gob, NB_GOS * KDIM / 8);
        {
            dim3 g(KDIM / 32, KDIM / 32, N_RELS + 1), bb(32, 8);
            transpose_cat<<<g, bb, 0, stream>>>(W_rel, W_loop, BTcat);
        }
        hist_dst<<<(N_EDGES + 255) / 256, 256, 0, stream>>>(dst, cnt);
        scan_offs<<<1, 1024, 0, stream>>>(cnt, offs);
        scatter_dst<<<(N_EDGES + 255) / 256, 256, 0, stream>>>(src, dst, etypes, offs, cursor, se);
        aggregate<<<N_NODES, 256, 0, stream>>>(offs, se, Acat);

        // hb = bf16([feat | agg] @ [W_loop; W_rel]^T + bias)   (K = 8192)
        {
            dim3 g(KDIM / 256, MPAD / 256);    // (4, 63) -> 252 wgs
            gemm256<0, KCAT><<<g, 512, 0, stream>>>(Acat, BTcat, bias, hb);
        }
        // out = sigmoid(hb @ go^T + |rad|)   (K = 1024)
        {
            dim3 g(NB_GOS / 256, MPAD / 256);  // (16, 63) -> 1008 wgs
            gemm256<2, KDIM><<<g, 512, 0, stream>>>(hb, gob, go_rad, out);
        }
        return;
    }

    // ---- fallback: rounds-3/4 path (~124 MB ws) ----
    char* p = (char*)d_ws;
    float* h            = (float*)p;            p += (size_t)N_NODES * KDIM * 4;
    unsigned short* fb  = (unsigned short*)p;   p += (size_t)N_NODES * KDIM * 2;
    unsigned short* wrT = (unsigned short*)p;   p += (size_t)N_RELS * KDIM * KDIM * 2;
    unsigned short* wlT = (unsigned short*)p;   p += (size_t)KDIM * KDIM * 2;
    unsigned short* gob = (unsigned short*)p;   p += (size_t)NB_GOS * KDIM * 2;
    int* cnt    = (int*)p;
    int* cursor = cnt + 8;
    int* offs   = cursor + 8;
    int* bucket = offs + 16;

    conv_bf16<<<(N_NODES * KDIM / 8 + 255) / 256, 256, 0, stream>>>(feat, fb, N_NODES * KDIM / 8);
    conv_bf16<<<(NB_GOS * KDIM / 8 + 255) / 256, 256, 0, stream>>>(go_emb, gob, NB_GOS * KDIM / 8);
    {
        dim3 g(KDIM / 32, KDIM / 32, N_RELS + 1), bb(32, 8);
        transpose_w<<<g, bb, 0, stream>>>(W_rel, W_loop, wrT, wlT);
    }
    init_buckets<<<(CAP2 + 255) / 256, 256, 0, stream>>>(cnt, cursor, bucket);
    count_etypes<<<(N_EDGES + 255) / 256, 256, 0, stream>>>(etypes, cnt);
    calc_offsets<<<1, 64, 0, stream>>>(cnt, offs);
    scatter_edges<<<(N_EDGES + 255) / 256, 256, 0, stream>>>(etypes, offs, cursor, bucket);
    {
        dim3 g(KDIM / BN, N_NODES / BM);
        mfma_gemm<0><<<g, 256, 0, stream>>>(fb, wlT, bias, h, nullptr, nullptr, nullptr, nullptr, KDIM);
    }
    {
        dim3 g(KDIM / BN, NTILE_E);
        mfma_gemm<1><<<g, 256, 0, stream>>>(fb, wrT, nullptr, h, src, dst, bucket, offs, KDIM);
    }
    conv_bf16<<<(N_NODES * KDIM / 8 + 255) / 256, 256, 0, stream>>>(h, fb, N_NODES * KDIM / 8);
    {
        dim3 g(NB_GOS / BN, N_NODES / BM);
        mfma_gemm<2><<<g, 256, 0, stream>>>(fb, gob, go_rad, out, nullptr, nullptr, nullptr, nullptr, KDIM);
    }
}

// Round 11
// 560.499 us; speedup vs baseline: 2.7971x; 1.0364x over previous
//
#include <hip/hip_runtime.h>
#include <math.h>

#define N_NODES 16000
#define N_EDGES 128000
#define KDIM 1024
#define N_RELS 7
#define NB_GOS 4096
#define KCAT (KDIM * (N_RELS + 1))     // 8192: [feat | agg r0..r6]
#define MPAD 16128                     // 63 * 256

#define BM 128
#define BN 128
#define BK 32
#define CAP2 (N_EDGES + N_RELS * BM)   // fallback path
#define NTILE_E (CAP2 / BM)

typedef __attribute__((ext_vector_type(8))) short bf16x8;
typedef __attribute__((ext_vector_type(8))) unsigned short u16x8;
typedef __attribute__((ext_vector_type(4))) float f32x4;

__device__ __forceinline__ unsigned short f2bf(float f) {
    union { float f; unsigned int u; } v; v.f = f;
    unsigned int u = v.u + 0x7FFFu + ((v.u >> 16) & 1u);   // RNE
    return (unsigned short)(u >> 16);
}

__device__ __forceinline__ float bf2f(unsigned short u) {
    union { unsigned int u; float f; } v; v.u = (unsigned int)u << 16;
    return v.f;
}

__device__ __forceinline__ void gload16(const void* g, void* lds) {
    __builtin_amdgcn_global_load_lds(
        (const __attribute__((address_space(1))) unsigned int*)g,
        (__attribute__((address_space(3))) unsigned int*)lds, 16, 0, 0);
}

// ---------------- prep kernels ----------------

__global__ __launch_bounds__(256) void conv_bf16(const float* __restrict__ in,
                                                 unsigned short* __restrict__ out, int n8) {
    int i = blockIdx.x * 256 + threadIdx.x;
    if (i >= n8) return;
    const float4* in4 = (const float4*)in;
    float4 x = in4[2 * i], y = in4[2 * i + 1];
    u16x8 o;
    o[0] = f2bf(x.x); o[1] = f2bf(x.y); o[2] = f2bf(x.z); o[3] = f2bf(x.w);
    o[4] = f2bf(y.x); o[5] = f2bf(y.y); o[6] = f2bf(y.z); o[7] = f2bf(y.w);
    *(u16x8*)&out[(size_t)i * 8] = o;
}

__global__ __launch_bounds__(256) void conv_cat(const float* __restrict__ in,
                                                unsigned short* __restrict__ Acat) {
    int i = blockIdx.x * 256 + threadIdx.x;
    if (i >= N_NODES * (KDIM / 8)) return;
    int n = i >> 7, c8 = (i & 127) * 8;
    const float4* in4 = (const float4*)(in + (size_t)n * KDIM + c8);
    float4 x = in4[0], y = in4[1];
    u16x8 o;
    o[0] = f2bf(x.x); o[1] = f2bf(x.y); o[2] = f2bf(x.z); o[3] = f2bf(x.w);
    o[4] = f2bf(y.x); o[5] = f2bf(y.y); o[6] = f2bf(y.z); o[7] = f2bf(y.w);
    *(u16x8*)&Acat[(size_t)n * KCAT + c8] = o;
}

__global__ void transpose_w(const float* __restrict__ Wrel,
                            const float* __restrict__ Wloop,
                            unsigned short* __restrict__ WrelT,
                            unsigned short* __restrict__ WloopT) {
    __shared__ float t[32][33];
    int z = blockIdx.z;
    const float* src = (z < N_RELS) ? Wrel + (size_t)z * KDIM * KDIM : Wloop;
    unsigned short* dst = (z < N_RELS) ? WrelT + (size_t)z * KDIM * KDIM : WloopT;
    int tx = threadIdx.x, ty = threadIdx.y;
    int x = blockIdx.x * 32 + tx;
    int y0 = blockIdx.y * 32;
    #pragma unroll
    for (int j = 0; j < 4; j++)
        t[ty + 8 * j][tx] = src[(size_t)(y0 + ty + 8 * j) * KDIM + x];
    __syncthreads();
    #pragma unroll
    for (int j = 0; j < 4; j++) {
        int n = blockIdx.x * 32 + ty + 8 * j;
        dst[(size_t)n * KDIM + y0 + tx] = f2bf(t[tx][ty + 8 * j]);
    }
}

__global__ void transpose_cat(const float* __restrict__ Wrel,
                              const float* __restrict__ Wloop,
                              unsigned short* __restrict__ BT) {
    __shared__ float t[32][33];
    int z = blockIdx.z;
    const float* src = (z == 0) ? Wloop : Wrel + (size_t)(z - 1) * KDIM * KDIM;
    int tx = threadIdx.x, ty = threadIdx.y;
    int x = blockIdx.x * 32 + tx;
    int y0 = blockIdx.y * 32;
    #pragma unroll
    for (int j = 0; j < 4; j++)
        t[ty + 8 * j][tx] = src[(size_t)(y0 + ty + 8 * j) * KDIM + x];
    __syncthreads();
    #pragma unroll
    for (int j = 0; j < 4; j++) {
        int o = blockIdx.x * 32 + ty + 8 * j;
        BT[(size_t)o * KCAT + z * KDIM + y0 + tx] = f2bf(t[tx][ty + 8 * j]);
    }
}

// ---------------- dst-sort + aggregation (fast path) ----------------

__global__ void zero_ints(int* p, int n) {
    int i = blockIdx.x * 256 + threadIdx.x;
    if (i < n) p[i] = 0;
}

__global__ void hist_dst(const int* __restrict__ dst, int* cnt) {
    int e = blockIdx.x * 256 + threadIdx.x;
    if (e < N_EDGES) atomicAdd(&cnt[dst[e]], 1);
}

__global__ __launch_bounds__(1024) void scan_offs(const int* __restrict__ cnt,
                                                  int* __restrict__ offs) {
    __shared__ int part[1024];
    int t = threadIdx.x;
    int base = t * 16;
    int local[16];
    int s = 0;
    if (base < N_NODES) {
        #pragma unroll
        for (int j = 0; j < 16; j++) { local[j] = cnt[base + j]; s += local[j]; }
    }
    part[t] = s;
    __syncthreads();
    for (int d = 1; d < 1024; d <<= 1) {
        int v = (t >= d) ? part[t - d] : 0;
        __syncthreads();
        part[t] += v;
        __syncthreads();
    }
    if (base < N_NODES) {
        int ex = (t == 0) ? 0 : part[t - 1];
        #pragma unroll
        for (int j = 0; j < 16; j++) { offs[base + j] = ex; ex += local[j]; }
        if (base + 16 == N_NODES) offs[N_NODES] = ex;
    }
}

__global__ void scatter_dst(const int* __restrict__ src, const int* __restrict__ dst,
                            const int* __restrict__ et, const int* __restrict__ offs,
                            int* cursor, int* __restrict__ se) {
    int e = blockIdx.x * 256 + threadIdx.x;
    if (e < N_EDGES) {
        int d = dst[e];
        int p = atomicAdd(&cursor[d], 1);
        se[offs[d] + p] = (src[e] << 3) | et[e];
    }
}

// per-node aggregation: reads src rows in BF16 from Acat's feat region,
// fp32 accumulate, bf16 store. (r10 win: halves read bytes vs fp32 feat.)
__global__ __launch_bounds__(256) void aggregate(const int* __restrict__ offs,
                                                 const int* __restrict__ se,
                                                 unsigned short* __restrict__ Acat) {
    int n = blockIdx.x;
    int t = threadIdx.x;
    int e0 = offs[n], e1 = offs[n + 1];
    float4 a0 = {0,0,0,0}, a1 = a0, a2 = a0, a3 = a0, a4 = a0, a5 = a0, a6 = a0;
    for (int i = e0; i < e1; i++) {
        int v = se[i];                      // wave-uniform
        int s = v >> 3, r = v & 7;
        ushort4 q = *(const ushort4*)&Acat[(size_t)s * KCAT + t * 4];
        float4 x = { bf2f(q.x), bf2f(q.y), bf2f(q.z), bf2f(q.w) };
        #define ADD4(a) { a.x += x.x; a.y += x.y; a.z += x.z; a.w += x.w; }
        switch (r) {                        // uniform branch (same edge blockwide)
            case 0: ADD4(a0) break; case 1: ADD4(a1) break;
            case 2: ADD4(a2) break; case 3: ADD4(a3) break;
            case 4: ADD4(a4) break; case 5: ADD4(a5) break;
            default: ADD4(a6) break;
        }
        #undef ADD4
    }
    unsigned short* row = Acat + (size_t)n * KCAT + KDIM;
    #define ST4(rr, a) { ushort4 o; o.x = f2bf(a.x); o.y = f2bf(a.y); \
                         o.z = f2bf(a.z); o.w = f2bf(a.w); \
                         *(ushort4*)(row + rr * KDIM + t * 4) = o; }
    ST4(0, a0) ST4(1, a1) ST4(2, a2) ST4(3, a3) ST4(4, a4) ST4(5, a5) ST4(6, a6)
    #undef ST4
}

// ======== 256x256 GEMM, BK=64, 2 K-tiles/iter, 4 fat phases, 1 barrier/phase ==
// MODE 0: hb = bf16(A @ BT^T + bias)        MODE 2: out = sigmoid(... + |rad|)
// vs r10: the mid-phase barrier (between ds_reads and MFMA) is REMOVED — it
// protected nothing (each phase's MFMA consumes all its own ds_reads, so reads
// retire before the wave reaches the END-phase barrier; every stage's target
// region had its last reader >=1 end-barrier earlier; vmcnt gates are at phase
// ends). With one barrier/phase, the 2 waves/SIMD can skew within a phase ->
// one wave's LDS reads overlap the other's MFMA (m114 mechanism).
// Phase = {ds_reads; stage-issues; MFMA(setprio); [vmcnt]; s_barrier}.
// Ledger (per wave, 2 loads per stage call):
//  P1: LDA(0,0) LDB(0,0->b0) LDB(0,1->b1); stage Ahi,Bhi(2t+1)->buf1 | 32 MFMA
//  P2: LDA(0,1); stage Alo,Blo(2t+2)->buf0 | 32 MFMA | vmcnt(4)
//  P3: LDA(1,0) LDB->b0,b1;  stage Ahi,Bhi(2t+2)->buf0 | 32 MFMA
//  P4: LDA(1,1); stage Alo,Blo(2t+3)->buf1 | 32 MFMA | vmcnt(4)

template<int MODE, int KD>
__global__ __launch_bounds__(512, 2) void gemm256(
    const unsigned short* __restrict__ A,    // [Mpad][KD] bf16
    const unsigned short* __restrict__ BT,   // [N][KD] bf16 (rows = out cols)
    const float* __restrict__ br,            // bias / rad
    void* __restrict__ outv)
{
    __shared__ unsigned short As[2][256 * 64];
    __shared__ unsigned short Bs[2][256 * 64];

    const int tid = threadIdx.x;
    const int l = tid & 63, w = tid >> 6;
    const int wm = w >> 2, wn = w & 3;
    const int lrow = l & 15, lhi = l >> 4, lx = l & 7;

    // bijective XCD swizzle; n-OUTER decomposition (B panel L2-resident per XCD)
    const int nwg = gridDim.x * gridDim.y;
    const int b = blockIdx.y * gridDim.x + blockIdx.x;
    const int q8 = nwg >> 3, r8 = nwg & 7;
    const int xcd = b & 7, idx = b >> 3;
    const int wg = (xcd < r8 ? xcd * (q8 + 1) : r8 * (q8 + 1) + (xcd - r8) * q8) + idx;
    const int m0 = (wg % gridDim.y) * 256;
    const int n0 = (wg / gridDim.y) * 256;

    const int NI = (KD >> 6) >> 1;

    const int rr = tid >> 3;                    // 0..63
    const int cc = (tid & 7) ^ (rr & 7);        // inverse-swizzled global chunk

    const unsigned short* gA = A + (size_t)(m0 + rr) * KD + cc * 8;
    const unsigned short* gB = BT + (size_t)(n0 + (rr & 31) + (rr >> 5) * 64) * KD + cc * 8;

    auto stageA = [&](int dbuf, int kt, int half) {
        #pragma unroll
        for (int j = 0; j < 2; j++)
            gload16(gA + (size_t)(j * 128 + half * 64) * KD + kt * 64,
                    &As[dbuf][(size_t)(w * 8 + j * 128 + half * 64) * 64]);
    };
    // B half = nh stripes: rows {0-31,64-95,128-159,192-223} (+32 for half=1)
    auto stageB = [&](int dbuf, int kt, int half) {
        #pragma unroll
        for (int j = 0; j < 2; j++)
            gload16(gB + (size_t)(j * 128 + half * 32) * KD + kt * 64,
                    &Bs[dbuf][(size_t)((w & 3) * 8 + (w >> 2) * 64 + j * 128 + half * 32) * 64]);
    };

    // prologue: tile0 all 4 halves + tile1 lo halves; retire tile0, leave 4
    stageA(0, 0, 0); stageB(0, 0, 0); stageA(0, 0, 1); stageB(0, 0, 1);
    stageA(1, 1, 0); stageB(1, 1, 0);
    asm volatile("s_waitcnt vmcnt(4)" ::: "memory");
    __builtin_amdgcn_s_barrier();

    f32x4 acc[8][4] = {};
    bf16x8 afr[4][2], b0[2][2], b1[2][2];

#define LDA(BUF, MH) do { _Pragma("unroll")                                   \
    for (int mi = 0; mi < 4; mi++) { _Pragma("unroll")                        \
        for (int ks = 0; ks < 2; ks++) {                                      \
            const int row_ = wm * 128 + (MH) * 64 + mi * 16 + lrow;           \
            const int ch_ = (ks * 4 + lhi) ^ lx;                              \
            afr[mi][ks] = *(const bf16x8*)&As[BUF][row_ * 64 + ch_ * 8];      \
        } } } while (0)

#define LDB(BUF, NH, DST) do { _Pragma("unroll")                              \
    for (int nj = 0; nj < 2; nj++) { _Pragma("unroll")                        \
        for (int ks = 0; ks < 2; ks++) {                                      \
            const int row_ = wn * 64 + (NH) * 32 + nj * 16 + lrow;            \
            const int ch_ = (ks * 4 + lhi) ^ lx;                              \
            DST[nj][ks] = *(const bf16x8*)&Bs[BUF][row_ * 64 + ch_ * 8];      \
        } } } while (0)

// one fat phase's MFMA cluster: 32 MFMA (MH x both NH quadrants), no barrier
#define MM2(MH) do {                                                          \
    __builtin_amdgcn_s_setprio(1);                                            \
    _Pragma("unroll")                                                         \
    for (int mi = 0; mi < 4; mi++) { _Pragma("unroll")                        \
        for (int nj = 0; nj < 2; nj++) { _Pragma("unroll")                    \
            for (int ks = 0; ks < 2; ks++) {                                  \
                acc[(MH)*4+mi][nj] = __builtin_amdgcn_mfma_f32_16x16x32_bf16( \
                    afr[mi][ks], b0[nj][ks], acc[(MH)*4+mi][nj], 0, 0, 0);    \
                acc[(MH)*4+mi][2+nj] = __builtin_amdgcn_mfma_f32_16x16x32_bf16( \
                    afr[mi][ks], b1[nj][ks], acc[(MH)*4+mi][2+nj], 0, 0, 0);  \
        } } }                                                                 \
    __builtin_amdgcn_s_setprio(0); } while (0)

    for (int t = 0; t < NI; t++) {
        const bool nl = (t + 1 < NI);
        // P1: tile 2t (buf0), MH0 x {NH0,NH1}
        LDA(0, 0); LDB(0, 0, b0); LDB(0, 1, b1);
        stageA(1, 2 * t + 1, 1); stageB(1, 2 * t + 1, 1);
        MM2(0);
        __builtin_amdgcn_s_barrier();
        // P2: tile 2t, MH1 (b0,b1 reused)
        LDA(0, 1);
        if (nl) { stageA(0, 2 * t + 2, 0); stageB(0, 2 * t + 2, 0); }
        MM2(1);
        if (nl) asm volatile("s_waitcnt vmcnt(4)" ::: "memory");
        else    asm volatile("s_waitcnt vmcnt(0)" ::: "memory");
        __builtin_amdgcn_s_barrier();
        // P3: tile 2t+1 (buf1), MH0
        LDA(1, 0); LDB(1, 0, b0); LDB(1, 1, b1);
        if (nl) { stageA(0, 2 * t + 2, 1); stageB(0, 2 * t + 2, 1); }
        MM2(0);
        __builtin_amdgcn_s_barrier();
        // P4: tile 2t+1, MH1
        LDA(1, 1);
        if (nl) { stageA(1, 2 * t + 3, 0); stageB(1, 2 * t + 3, 0); }
        MM2(1);
        if (nl) asm volatile("s_waitcnt vmcnt(4)" ::: "memory");
        else    asm volatile("s_waitcnt vmcnt(0)" ::: "memory");
        __builtin_amdgcn_s_barrier();
    }
#undef LDA
#undef LDB
#undef MM2

    // epilogue — C/D layout: col = lane&15, row = (lane>>4)*4 + reg
    const int cl = l & 15, rh = (l >> 4) * 4;
    float brv[4];
    #pragma unroll
    for (int nj = 0; nj < 4; nj++) brv[nj] = br[n0 + wn * 64 + nj * 16 + cl];
    #pragma unroll
    for (int mi = 0; mi < 8; mi++) {
        #pragma unroll
        for (int r4 = 0; r4 < 4; r4++) {
            const int row = m0 + wm * 128 + mi * 16 + rh + r4;
            if (MODE == 2 && row >= N_NODES) continue;
            #pragma unroll
            for (int nj = 0; nj < 4; nj++) {
                const int col = n0 + wn * 64 + nj * 16 + cl;
                float x = acc[mi][nj][r4];
                if (MODE == 0) {
                    ((unsigned short*)outv)[(size_t)row * KDIM + col] = f2bf(x + brv[nj]);
                } else {
                    x += fabsf(brv[nj]);
                    ((float*)outv)[(size_t)row * (size_t)NB_GOS + col] =
                        1.0f / (1.0f + __expf(-x));
                }
            }
        }
    }
}

// ---------------- fallback 128x128 GEMM (rounds 3/4, unchanged) ----------------

__global__ void init_buckets(int* cnt, int* cursor, int* bucket) {
    int i = blockIdx.x * 256 + threadIdx.x;
    if (i < 8) { cnt[i] = 0; cursor[i] = 0; }
    if (i < CAP2) bucket[i] = -1;
}

__global__ __launch_bounds__(256) void count_etypes(const int* __restrict__ et, int* cnt) {
    __shared__ int lc[N_RELS];
    if (threadIdx.x < N_RELS) lc[threadIdx.x] = 0;
    __syncthreads();
    int e = blockIdx.x * 256 + threadIdx.x;
    if (e < N_EDGES) atomicAdd(&lc[et[e]], 1);
    __syncthreads();
    if (threadIdx.x < N_RELS) atomicAdd(&cnt[threadIdx.x], lc[threadIdx.x]);
}

__global__ void calc_offsets(const int* __restrict__ cnt, int* offs) {
    if (blockIdx.x == 0 && threadIdx.x == 0) {
        int acc = 0;
        offs[0] = 0;
        for (int r = 0; r < N_RELS; r++) {
            acc += ((cnt[r] + BM - 1) / BM) * BM;
            offs[r + 1] = acc;
        }
    }
}

__global__ __launch_bounds__(256) void scatter_edges(const int* __restrict__ et,
                                                     const int* __restrict__ offs,
                                                     int* cursor, int* bucket) {
    __shared__ int lc[N_RELS];
    __shared__ int lbase[N_RELS];
    if (threadIdx.x < N_RELS) lc[threadIdx.x] = 0;
    __syncthreads();
    int e = blockIdx.x * 256 + threadIdx.x;
    int r = 0, my = 0;
    bool valid = (e < N_EDGES);
    if (valid) { r = et[e]; my = atomicAdd(&lc[r], 1); }
    __syncthreads();
    if (threadIdx.x < N_RELS)
        lbase[threadIdx.x] = atomicAdd(&cursor[threadIdx.x], lc[threadIdx.x]);
    __syncthreads();
    if (valid) bucket[offs[r] + lbase[r] + my] = e;
}

template<int MODE>
__global__ __launch_bounds__(256) void mfma_gemm(
    const unsigned short* __restrict__ A,
    const unsigned short* __restrict__ BT,
    const float* __restrict__ br,
    float* __restrict__ out,
    const int* __restrict__ src,
    const int* __restrict__ dst,
    const int* __restrict__ bucket,
    const int* __restrict__ offs,
    int kd)
{
    __shared__ unsigned short As[BM * BK];
    __shared__ unsigned short Bs[BN * BK];
    __shared__ int s_src[BM];
    __shared__ int s_dst[BM];

    const int tid = threadIdx.x;
    const int l = tid & 63;
    const int w = tid >> 6;
    const int wr = w >> 1, wc = w & 1;

    const int nwg = gridDim.x * gridDim.y;
    const int b = blockIdx.y * gridDim.x + blockIdx.x;
    const int cpx = nwg >> 3;
    const int swz = (b & 7) * cpx + (b >> 3);
    const int n0 = (swz / gridDim.y) * BN;
    const int m0 = (swz % gridDim.y) * BM;

    const unsigned short* Bb = BT;
    if (MODE == 1) {
        int rel = -1;
        #pragma unroll
        for (int q = 0; q < N_RELS; q++)
            if (m0 >= offs[q] && m0 < offs[q + 1]) rel = q;
        if (rel < 0) return;
        Bb = BT + (size_t)rel * KDIM * KDIM;
        if (tid < BM) {
            int e = bucket[m0 + tid];
            s_src[tid] = (e >= 0) ? src[e] : -1;
            s_dst[tid] = (e >= 0) ? dst[e] : -1;
        }
        __syncthreads();
    }

    f32x4 acc[4][4] = {};

    const int s0 = tid, s1 = tid + 256;
    const int r0 = s0 >> 2, kc0 = (s0 & 3) * 8;
    const int r1 = s1 >> 2, kc1 = (s1 & 3) * 8;
    unsigned short* ldsA0 = As + (w * 64) * 8;
    unsigned short* ldsA1 = As + (w * 64 + 256) * 8;
    unsigned short* ldsB0 = Bs + (w * 64) * 8;
    unsigned short* ldsB1 = Bs + (w * 64 + 256) * 8;

    size_t arow0, arow1;
    if (MODE == 1) {
        int sr0 = s_src[r0]; arow0 = (sr0 < 0) ? 0 : (size_t)sr0;
        int sr1 = s_src[r1]; arow1 = (sr1 < 0) ? 0 : (size_t)sr1;
    } else {
        arow0 = (size_t)(m0 + r0);
        arow1 = (size_t)(m0 + r1);
    }
    const size_t brow0 = (size_t)(n0 + r0), brow1 = (size_t)(n0 + r1);

    const int fa = (wr * 64 + (l & 15)) * BK + (l >> 4) * 8;
    const int fb = (wc * 64 + (l & 15)) * BK + (l >> 4) * 8;

    for (int k0 = 0; k0 < kd; k0 += BK) {
        gload16(A + arow0 * kd + k0 + kc0, ldsA0);
        gload16(A + arow1 * kd + k0 + kc1, ldsA1);
        gload16(Bb + brow0 * kd + k0 + kc0, ldsB0);
        gload16(Bb + brow1 * kd + k0 + kc1, ldsB1);
        __syncthreads();

        bf16x8 a[4], bfr[4];
        #pragma unroll
        for (int mi = 0; mi < 4; mi++)
            a[mi] = *(const bf16x8*)&As[fa + mi * 16 * BK];
        #pragma unroll
        for (int nj = 0; nj < 4; nj++)
            bfr[nj] = *(const bf16x8*)&Bs[fb + nj * 16 * BK];
        #pragma unroll
        for (int mi = 0; mi < 4; mi++)
            #pragma unroll
            for (int nj = 0; nj < 4; nj++)
                acc[mi][nj] = __builtin_amdgcn_mfma_f32_16x16x32_bf16(a[mi], bfr[nj], acc[mi][nj], 0, 0, 0);
        __syncthreads();
    }

    const int cl = l & 15, rh = (l >> 4) * 4;
    #pragma unroll
    for (int mi = 0; mi < 4; mi++) {
        #pragma unroll
        for (int r4 = 0; r4 < 4; r4++) {
            const int row = wr * 64 + mi * 16 + rh + r4;
            if (MODE == 1) {
                const int d = s_dst[row];
                if (d >= 0) {
                    #pragma unroll
                    for (int nj = 0; nj < 4; nj++) {
                        const int col = n0 + wc * 64 + nj * 16 + cl;
                        atomicAdd(&out[(size_t)d * KDIM + col], acc[mi][nj][r4]);
                    }
                }
            } else if (MODE == 0) {
                #pragma unroll
                for (int nj = 0; nj < 4; nj++) {
                    const int col = n0 + wc * 64 + nj * 16 + cl;
                    out[(size_t)(m0 + row) * KDIM + col] = acc[mi][nj][r4] + br[col];
                }
            } else {
                #pragma unroll
                for (int nj = 0; nj < 4; nj++) {
                    const int col = n0 + wc * 64 + nj * 16 + cl;
                    float x = acc[mi][nj][r4] + fabsf(br[col]);
                    out[(size_t)(m0 + row) * (size_t)NB_GOS + col] = 1.0f / (1.0f + expf(-x));
                }
            }
        }
    }
}

// ---------------- launch ----------------

extern "C" void kernel_launch(void* const* d_in, const int* in_sizes, int n_in,
                              void* d_out, int out_size, void* d_ws, size_t ws_size,
                              hipStream_t stream) {
    const float* feat   = (const float*)d_in[0];
    const int*   src    = (const int*)d_in[1];
    const int*   dst    = (const int*)d_in[2];
    const int*   etypes = (const int*)d_in[3];
    const float* W_rel  = (const float*)d_in[4];
    const float* W_loop = (const float*)d_in[5];
    const float* bias   = (const float*)d_in[6];
    const float* go_emb = (const float*)d_in[7];
    const float* go_rad = (const float*)d_in[8];
    float* out = (float*)d_out;

    // ---- fast-path workspace layout (~323 MB) ----
    const size_t ACAT_B = (size_t)MPAD * KCAT * 2;      // 264,241,152
    const size_t HB_B   = (size_t)MPAD * KDIM * 2;      //  33,030,144 (bf16 h)
    const size_t BTC_B  = (size_t)KDIM * KCAT * 2;      //  16,777,216
    const size_t GOB_B  = (size_t)NB_GOS * KDIM * 2;    //   8,388,608
    const size_t CNT_B  = 16384 * 4;
    const size_t NEED   = ACAT_B + HB_B + BTC_B + GOB_B + 3 * CNT_B + (size_t)N_EDGES * 4;

    if (ws_size >= NEED) {
        char* p = (char*)d_ws;
        unsigned short* Acat  = (unsigned short*)p;  p += ACAT_B;
        unsigned short* hb    = (unsigned short*)p;  p += HB_B;
        unsigned short* BTcat = (unsigned short*)p;  p += BTC_B;
        unsigned short* gob   = (unsigned short*)p;  p += GOB_B;
        int* cnt    = (int*)p;                       p += CNT_B;
        int* cursor = (int*)p;                       p += CNT_B;
        int* offs   = (int*)p;                       p += CNT_B;
        int* se     = (int*)p;

        zero_ints<<<(2 * 16384 + 255) / 256, 256, 0, stream>>>(cnt, 2 * 16384);
        conv_cat<<<(N_NODES * (KDIM / 8) + 255) / 256, 256, 0, stream>>>(feat, Acat);
        conv_bf16<<<(NB_GOS * KDIM / 8 + 255) / 256, 256, 0, stream>>>(go_emb, gob, NB_GOS * KDIM / 8);
        {
            dim3 g(KDIM / 32, KDIM / 32, N_RELS + 1), bb(32, 8);
            transpose_cat<<<g, bb, 0, stream>>>(W_rel, W_loop, BTcat);
        }
        hist_dst<<<(N_EDGES + 255) / 256, 256, 0, stream>>>(dst, cnt);
        scan_offs<<<1, 1024, 0, stream>>>(cnt, offs);
        scatter_dst<<<(N_EDGES + 255) / 256, 256, 0, stream>>>(src, dst, etypes, offs, cursor, se);
        aggregate<<<N_NODES, 256, 0, stream>>>(offs, se, Acat);

        // hb = bf16([feat | agg] @ [W_loop; W_rel]^T + bias)   (K = 8192)
        {
            dim3 g(KDIM / 256, MPAD / 256);    // (4, 63) -> 252 wgs
            gemm256<0, KCAT><<<g, 512, 0, stream>>>(Acat, BTcat, bias, hb);
        }
        // out = sigmoid(hb @ go^T + |rad|)   (K = 1024)
        {
            dim3 g(NB_GOS / 256, MPAD / 256);  // (16, 63) -> 1008 wgs
            gemm256<2, KDIM><<<g, 512, 0, stream>>>(hb, gob, go_rad, out);
        }
        return;
    }

    // ---- fallback: rounds-3/4 path (~124 MB ws) ----
    char* p = (char*)d_ws;
    float* h            = (float*)p;            p += (size_t)N_NODES * KDIM * 4;
    unsigned short* fb  = (unsigned short*)p;   p += (size_t)N_NODES * KDIM * 2;
    unsigned short* wrT = (unsigned short*)p;   p += (size_t)N_RELS * KDIM * KDIM * 2;
    unsigned short* wlT = (unsigned short*)p;   p += (size_t)KDIM * KDIM * 2;
    unsigned short* gob = (unsigned short*)p;   p += (size_t)NB_GOS * KDIM * 2;
    int* cnt    = (int*)p;
    int* cursor = cnt + 8;
    int* offs   = cursor + 8;
    int* bucket = offs + 16;

    conv_bf16<<<(N_NODES * KDIM / 8 + 255) / 256, 256, 0, stream>>>(feat, fb, N_NODES * KDIM / 8);
    conv_bf16<<<(NB_GOS * KDIM / 8 + 255) / 256, 256, 0, stream>>>(go_emb, gob, NB_GOS * KDIM / 8);
    {
        dim3 g(KDIM / 32, KDIM / 32, N_RELS + 1), bb(32, 8);
        transpose_w<<<g, bb, 0, stream>>>(W_rel, W_loop, wrT, wlT);
    }
    init_buckets<<<(CAP2 + 255) / 256, 256, 0, stream>>>(cnt, cursor, bucket);
    count_etypes<<<(N_EDGES + 255) / 256, 256, 0, stream>>>(etypes, cnt);
    calc_offsets<<<1, 64, 0, stream>>>(cnt, offs);
    scatter_edges<<<(N_EDGES + 255) / 256, 256, 0, stream>>>(etypes, offs, cursor, bucket);
    {
        dim3 g(KDIM / BN, N_NODES / BM);
        mfma_gemm<0><<<g, 256, 0, stream>>>(fb, wlT, bias, h, nullptr, nullptr, nullptr, nullptr, KDIM);
    }
    {
        dim3 g(KDIM / BN, NTILE_E);
        mfma_gemm<1><<<g, 256, 0, stream>>>(fb, wrT, nullptr, h, src, dst, bucket, offs, KDIM);
    }
    conv_bf16<<<(N_NODES * KDIM / 8 + 255) / 256, 256, 0, stream>>>(h, fb, N_NODES * KDIM / 8);
    {
        dim3 g(NB_GOS / BN, N_NODES / BM);
        mfma_gemm<2><<<g, 256, 0, stream>>>(fb, gob, go_rad, out, nullptr, nullptr, nullptr, nullptr, KDIM);
    }
}